// Round 11
// baseline (115.403 us; speedup 1.0000x reference)
//
#include <hip/hip_runtime.h>

#define T_LEN 1024
#define EMB   512
#define NH    8
#define HD    64
#define PDIM  32
#define MDIM  4
#define FDIM  128   // PDIM*MDIM
#define TC    64    // chunk length
#define NC    16    // T_LEN/TC

typedef __attribute__((ext_vector_type(8))) short bf16x8;
typedef __attribute__((ext_vector_type(4))) float f32x4;

__device__ __forceinline__ unsigned short f2bf(float f) {
    unsigned u = __float_as_uint(f);
    unsigned r = u + 0x7fffu + ((u >> 16) & 1u);   // RNE
    return (unsigned short)(r >> 16);
}
__device__ __forceinline__ float bf2f(unsigned short h) {
    return __uint_as_float(((unsigned)h) << 16);
}
__device__ __forceinline__ void split4(float4 v, ushort4& h4, ushort4& l4) {
    h4.x = f2bf(v.x); l4.x = f2bf(v.x - bf2f(h4.x));
    h4.y = f2bf(v.y); l4.y = f2bf(v.y - bf2f(h4.y));
    h4.z = f2bf(v.z); l4.z = f2bf(v.z - bf2f(h4.z));
    h4.w = f2bf(v.w); l4.w = f2bf(v.w - bf2f(h4.w));
}
// split-bf16 product: (ah+al)*(bh+bl) ~= ah*bh + ah*bl + al*bh
__device__ __forceinline__ f32x4 mm3(bf16x8 ah, bf16x8 al, bf16x8 bh, bf16x8 bl, f32x4 acc) {
    acc = __builtin_amdgcn_mfma_f32_16x16x32_bf16(ah, bh, acc, 0, 0, 0);
    acc = __builtin_amdgcn_mfma_f32_16x16x32_bf16(ah, bl, acc, 0, 0, 0);
    acc = __builtin_amdgcn_mfma_f32_16x16x32_bf16(al, bh, acc, 0, 0, 0);
    return acc;
}
#define LD8(TILE, ROW, KB) (*reinterpret_cast<const bf16x8*>(&TILE[ROW][KB]))

// ---------------------------------------------------------------------------
// Kernel 0: pre-split f32 -> bf16 hi/lo planes for x, qkv_w, out_w.
// ---------------------------------------------------------------------------
__global__ __launch_bounds__(256) void k_cvt(
    const float* __restrict__ X, const float* __restrict__ Wq,
    const float* __restrict__ Wo,
    unsigned short* __restrict__ Xhi, unsigned short* __restrict__ Xlo,
    unsigned short* __restrict__ Whi, unsigned short* __restrict__ Wlo,
    unsigned short* __restrict__ Ohi, unsigned short* __restrict__ Olo)
{
    int i = (blockIdx.x * 256 + threadIdx.x) * 4;
    const float* src; unsigned short *dh, *dl; int off;
    if (i < 524288)       { src = X;  dh = Xhi; dl = Xlo; off = i; }
    else if (i < 1310720) { src = Wq; dh = Whi; dl = Wlo; off = i - 524288; }
    else                  { src = Wo; dh = Ohi; dl = Olo; off = i - 1310720; }
    float4 v = *reinterpret_cast<const float4*>(&src[off]);
    ushort4 h4, l4; split4(v, h4, l4);
    *reinterpret_cast<ushort4*>(&dh[off]) = h4;
    *reinterpret_cast<ushort4*>(&dl[off]) = l4;
}

// ---------------------------------------------------------------------------
// Kernel 1: qkv GEMM, 128x64 tile, 512 threads (8 waves, 4x2 wave grid).
// Pre-split operands, pure int4 staging, fused features epilogue.
// ---------------------------------------------------------------------------
__global__ __launch_bounds__(512) void k_qkv_mfma(
    const unsigned short* __restrict__ Xhi, const unsigned short* __restrict__ Xlo,
    const unsigned short* __restrict__ Whi, const unsigned short* __restrict__ Wlo,
    const float* __restrict__ bias,
    const float* __restrict__ poly_proj, const float* __restrict__ omega,
    unsigned short* __restrict__ Vhi, unsigned short* __restrict__ Vlo,
    unsigned short* __restrict__ qfhi, unsigned short* __restrict__ qflo,
    unsigned short* __restrict__ kfhi, unsigned short* __restrict__ kflo)
{
    const int j0 = blockIdx.x * 64;    // N=1536
    const int t0 = blockIdx.y * 128;   // M=1024
    __shared__ __align__(16) unsigned short Ahi[128][72], Alo[128][72],
                                            Bhi[64][72],  Blo[64][72];
    __shared__ float poly_s[128][33];
    __shared__ float prf_s[128][5];
    __shared__ float nrm2[2][128];
    const int tid = threadIdx.x, lane = tid & 63, wid = tid >> 6;
    const int wrow = (wid >> 1) * 32, wcol = (wid & 1) * 32;
    const int lr = lane & 15, lg = lane >> 4;
    f32x4 acc[2][2];
    #pragma unroll
    for (int i = 0; i < 2; ++i)
        #pragma unroll
        for (int j = 0; j < 2; ++j) acc[i][j] = (f32x4){0.f, 0.f, 0.f, 0.f};

    for (int k0 = 0; k0 < 512; k0 += 64) {
        #pragma unroll
        for (int l = 0; l < 2; ++l) {             // A: 128 rows (1024 chunks)
            int ch = tid + l * 512;
            int row = ch >> 3, sg = (ch & 7) * 8;
            size_t ao = (size_t)(t0 + row) * 512 + k0 + sg;
            *reinterpret_cast<int4*>(&Ahi[row][sg]) = *reinterpret_cast<const int4*>(&Xhi[ao]);
            *reinterpret_cast<int4*>(&Alo[row][sg]) = *reinterpret_cast<const int4*>(&Xlo[ao]);
        }
        {                                          // B: 64 rows (512 chunks)
            int row = tid >> 3, sg = (tid & 7) * 8;
            size_t bo = (size_t)(j0 + row) * 512 + k0 + sg;
            *reinterpret_cast<int4*>(&Bhi[row][sg]) = *reinterpret_cast<const int4*>(&Whi[bo]);
            *reinterpret_cast<int4*>(&Blo[row][sg]) = *reinterpret_cast<const int4*>(&Wlo[bo]);
        }
        __syncthreads();
        #pragma unroll
        for (int kh = 0; kh < 2; ++kh) {
            const int kb = kh * 32 + lg * 8;
            bf16x8 ah0 = LD8(Ahi, wrow + lr, kb),      ah1 = LD8(Ahi, wrow + 16 + lr, kb);
            bf16x8 al0 = LD8(Alo, wrow + lr, kb),      al1 = LD8(Alo, wrow + 16 + lr, kb);
            bf16x8 bh0 = LD8(Bhi, wcol + lr, kb),      bh1 = LD8(Bhi, wcol + 16 + lr, kb);
            bf16x8 bl0 = LD8(Blo, wcol + lr, kb),      bl1 = LD8(Blo, wcol + 16 + lr, kb);
            acc[0][0] = mm3(ah0, al0, bh0, bl0, acc[0][0]);
            acc[0][1] = mm3(ah0, al0, bh1, bl1, acc[0][1]);
            acc[1][0] = mm3(ah1, al1, bh0, bl0, acc[1][0]);
            acc[1][1] = mm3(ah1, al1, bh1, bl1, acc[1][1]);
        }
        __syncthreads();
    }
    const int which = j0 >> 9;
    const int h = (j0 & 511) >> 6;

    if (which == 2) {   // v output as bf16 hi/lo planes (coalesced)
        #pragma unroll
        for (int i = 0; i < 2; ++i)
            #pragma unroll
            for (int j = 0; j < 2; ++j)
                #pragma unroll
                for (int r = 0; r < 4; ++r) {
                    int row = wrow + i * 16 + lg * 4 + r;
                    int col = wcol + j * 16 + lr;
                    float val = acc[i][j][r] + bias[j0 + col];
                    unsigned short hv = f2bf(val);
                    size_t vi = (size_t)(h * T_LEN + t0 + row) * HD + col;
                    Vhi[vi] = hv; Vlo[vi] = f2bf(val - bf2f(hv));
                }
        return;
    }

    // ---- fused features (128 rows) ----
    #pragma unroll
    for (int i = 0; i < 2; ++i) {
        #pragma unroll
        for (int r = 0; r < 4; ++r) {
            int row = wrow + i * 16 + lg * 4 + r;
            float ss = 0.f;
            #pragma unroll
            for (int j = 0; j < 2; ++j) {
                int col = wcol + j * 16 + lr;
                float zv = acc[i][j][r] + bias[j0 + col];
                ss = fmaf(zv, zv, ss);
                unsigned short hv = f2bf(zv);
                Ahi[row][col] = hv;
                Alo[row][col] = f2bf(zv - bf2f(hv));
            }
            ss += __shfl_xor(ss, 1, 64);
            ss += __shfl_xor(ss, 2, 64);
            ss += __shfl_xor(ss, 4, 64);
            ss += __shfl_xor(ss, 8, 64);
            if (lr == 0) nrm2[wid & 1][row] = ss;
        }
    }
    {   // Bp = [P^T | om^T | 0pad] (48 x 64) into Bhi/Blo
        const float* P = poly_proj + (size_t)h * 64 * 32;   // [d][p]
        int d = tid >> 3, p4 = (tid & 7) * 4;
        #pragma unroll
        for (int e = 0; e < 4; ++e) {
            float pv = P[d * 32 + p4 + e];
            unsigned short hv = f2bf(pv);
            Bhi[p4 + e][d] = hv;
            Blo[p4 + e][d] = f2bf(pv - bf2f(hv));
        }
        if (tid < 64) {
            const float* Om = omega + (size_t)h * 64 * 4;   // [d][m]
            float4 om = *reinterpret_cast<const float4*>(&Om[tid * 4]);
            float oa[4] = {om.x, om.y, om.z, om.w};
            #pragma unroll
            for (int m = 0; m < 4; ++m) {
                unsigned short hv = f2bf(oa[m]);
                Bhi[32 + m][tid] = hv;
                Blo[32 + m][tid] = f2bf(oa[m] - bf2f(hv));
            }
        }
        for (int rr = tid; rr < 12 * 64; rr += 512) {
            int row = 36 + (rr >> 6), dd = rr & 63;
            Bhi[row][dd] = 0; Blo[row][dd] = 0;
        }
    }
    __syncthreads();
    const int mrow = wid * 16;            // 8 waves x 16 rows = 128
    f32x4 g[3];
    g[0] = g[1] = g[2] = (f32x4){0.f, 0.f, 0.f, 0.f};
    #pragma unroll
    for (int kh = 0; kh < 2; ++kh) {
        const int kb = kh * 32 + lg * 8;
        bf16x8 ah = LD8(Ahi, mrow + lr, kb), al = LD8(Alo, mrow + lr, kb);
        #pragma unroll
        for (int j = 0; j < 3; ++j) {
            bf16x8 bh = LD8(Bhi, j * 16 + lr, kb), bl = LD8(Blo, j * 16 + lr, kb);
            g[j] = mm3(ah, al, bh, bl, g[j]);
        }
    }
    const float S_NODE = (float)(1.0 / 2.000001);
    const float SQRT2S = sqrtf(2.0f * S_NODE);
    #pragma unroll
    for (int r = 0; r < 4; ++r) {
        int row = mrow + lg * 4 + r;
        float rn = 1.0f / fmaxf(sqrtf(nrm2[0][row] + nrm2[1][row]), 1e-12f);
        #pragma unroll
        for (int j = 0; j < 3; ++j) {
            float gv = g[j][r] * rn;
            if (j < 2) poly_s[row][j * 16 + lr] = gv * gv;
            else if (lr < 4) {
                float arg = fminf(fmaxf(fmaf(gv, SQRT2S, -S_NODE), -20.0f), 20.0f);
                prf_s[row][lr] = expf(arg) * 0.5f;
            }
        }
    }
    {
        int row = mrow + (lane >> 2), fq = lane & 3;
        float pr[8], pf[4];
        #pragma unroll
        for (int e = 0; e < 8; ++e) pr[e] = poly_s[row][fq * 8 + e];
        #pragma unroll
        for (int m = 0; m < 4; ++m) pf[m] = prf_s[row][m];
        int4 hi4[4], lo4[4];
        unsigned short* hp = reinterpret_cast<unsigned short*>(hi4);
        unsigned short* lp = reinterpret_cast<unsigned short*>(lo4);
        #pragma unroll
        for (int e = 0; e < 8; ++e)
            #pragma unroll
            for (int m = 0; m < 4; ++m) {
                float val = pr[e] * pf[m];
                unsigned short hv = f2bf(val);
                hp[e * 4 + m] = hv;
                lp[e * 4 + m] = f2bf(val - bf2f(hv));
            }
        unsigned short* dhi = (which == 0) ? qfhi : kfhi;
        unsigned short* dlo = (which == 0) ? qflo : kflo;
        size_t base = (size_t)(h * T_LEN + t0 + row) * FDIM + fq * 32;
        #pragma unroll
        for (int s = 0; s < 4; ++s) {
            *reinterpret_cast<int4*>(&dhi[base + s * 8]) = hi4[s];
            *reinterpret_cast<int4*>(&dlo[base + s * 8]) = lo4[s];
        }
    }
}

// ---------------------------------------------------------------------------
// Kernel 6: y = attn @ out_w^T + out_b. All operands pre-split: int4 staging.
// ---------------------------------------------------------------------------
__global__ __launch_bounds__(256) void k_out_mfma(
    const unsigned short* __restrict__ AThi, const unsigned short* __restrict__ ATlo,
    const unsigned short* __restrict__ Ohi, const unsigned short* __restrict__ Olo,
    const float* __restrict__ bias, float* __restrict__ Y)
{
    const int j0 = blockIdx.x * 64;
    const int t0 = blockIdx.y * 64;
    __shared__ __align__(16) unsigned short Ahi[64][80], Alo[64][80],
                                            Bhi[64][80], Blo[64][80];
    const int tid = threadIdx.x, lane = tid & 63, wid = tid >> 6;
    const int wrow = (wid >> 1) * 32, wcol = (wid & 1) * 32;
    const int lr = lane & 15, lg = lane >> 4;
    f32x4 acc[2][2];
    #pragma unroll
    for (int i = 0; i < 2; ++i)
        #pragma unroll
        for (int j = 0; j < 2; ++j) acc[i][j] = (f32x4){0.f, 0.f, 0.f, 0.f};

    for (int k0 = 0; k0 < 512; k0 += 64) {
        #pragma unroll
        for (int l = 0; l < 2; ++l) {
            int ch = tid + l * 256;
            int row = ch >> 3, sg = (ch & 7) * 8;
            size_t ao = (size_t)(t0 + row) * 512 + k0 + sg;
            size_t bo = (size_t)(j0 + row) * 512 + k0 + sg;
            *reinterpret_cast<int4*>(&Ahi[row][sg]) = *reinterpret_cast<const int4*>(&AThi[ao]);
            *reinterpret_cast<int4*>(&Alo[row][sg]) = *reinterpret_cast<const int4*>(&ATlo[ao]);
            *reinterpret_cast<int4*>(&Bhi[row][sg]) = *reinterpret_cast<const int4*>(&Ohi[bo]);
            *reinterpret_cast<int4*>(&Blo[row][sg]) = *reinterpret_cast<const int4*>(&Olo[bo]);
        }
        __syncthreads();
        #pragma unroll
        for (int kh = 0; kh < 2; ++kh) {
            const int kb = kh * 32 + lg * 8;
            bf16x8 ah0 = LD8(Ahi, wrow + lr, kb),      ah1 = LD8(Ahi, wrow + 16 + lr, kb);
            bf16x8 al0 = LD8(Alo, wrow + lr, kb),      al1 = LD8(Alo, wrow + 16 + lr, kb);
            bf16x8 bh0 = LD8(Bhi, wcol + lr, kb),      bh1 = LD8(Bhi, wcol + 16 + lr, kb);
            bf16x8 bl0 = LD8(Blo, wcol + lr, kb),      bl1 = LD8(Blo, wcol + 16 + lr, kb);
            acc[0][0] = mm3(ah0, al0, bh0, bl0, acc[0][0]);
            acc[0][1] = mm3(ah0, al0, bh1, bl1, acc[0][1]);
            acc[1][0] = mm3(ah1, al1, bh0, bl0, acc[1][0]);
            acc[1][1] = mm3(ah1, al1, bh1, bl1, acc[1][1]);
        }
        __syncthreads();
    }
    #pragma unroll
    for (int i = 0; i < 2; ++i)
        #pragma unroll
        for (int j = 0; j < 2; ++j)
            #pragma unroll
            for (int r = 0; r < 4; ++r) {
                int row = wrow + i * 16 + lg * 4 + r;
                int col = wcol + j * 16 + lr;
                Y[(size_t)(t0 + row) * EMB + j0 + col] = acc[i][j][r] + bias[j0 + col];
            }
}

// ---------------------------------------------------------------------------
// Kernel 3: per-chunk SchT[d][f] = (V^T kf) via MFMA; dumps Vt planes (fh==0)
// and z column sums.
// ---------------------------------------------------------------------------
__global__ __launch_bounds__(256) void k_chunk_kv(
    const unsigned short* __restrict__ kfhi, const unsigned short* __restrict__ kflo,
    const unsigned short* __restrict__ Vhi, const unsigned short* __restrict__ Vlo,
    float* __restrict__ SchT, float* __restrict__ zch,
    unsigned short* __restrict__ Vthi, unsigned short* __restrict__ Vtlo)
{
    const int b = blockIdx.x;
    const int fh = b & 1, hc = b >> 1, h = hc >> 4, c = hc & 15;
    const int t0 = c * TC;
    const int tid = threadIdx.x, lane = tid & 63, wid = tid >> 6;
    const int wrow = (wid >> 1) * 32, wcol = (wid & 1) * 32;
    const int lr = lane & 15, lg = lane >> 4;
    __shared__ __align__(16) unsigned short Khi[64][80], Klo[64][80],   // kfT
                                            Ghi[64][80], Glo[64][80];   // Vt
    #pragma unroll
    for (int l = 0; l < 2; ++l) {   // kfT: transpose from kf (swizzled)
        int ch = tid + l * 256;
        int t = ch >> 3, f8 = (ch & 7) * 8;
        int tb = t >> 3, tl = t & 7, m = f8 >> 3;
        size_t ko = (size_t)((h << 10) + t0 + t) * FDIM + fh * 64 + f8;
        int4 hv = *reinterpret_cast<const int4*>(&kfhi[ko]);
        int4 lv = *reinterpret_cast<const int4*>(&kflo[ko]);
        const unsigned short* hp = reinterpret_cast<const unsigned short*>(&hv);
        const unsigned short* lp = reinterpret_cast<const unsigned short*>(&lv);
        int col = ((tb ^ m) << 3) + tl;
        #pragma unroll
        for (int j = 0; j < 8; ++j) {
            Khi[f8 + j][col] = hp[j];
            Klo[f8 + j][col] = lp[j];
        }
    }
    #pragma unroll
    for (int l = 0; l < 4; ++l) {   // Vt: transpose from V planes (swizzled)
        int ch = tid + l * 256;     // 0..1023
        int plane = ch >> 9, rem = ch & 511;
        int t = rem >> 3, d8 = (rem & 7) * 8;
        int tb = t >> 3, tl = t & 7;
        const unsigned short* src = plane ? Vlo : Vhi;
        int4 vv = *reinterpret_cast<const int4*>(&src[(size_t)((h << 10) + t0 + t) * HD + d8]);
        const unsigned short* vp = reinterpret_cast<const unsigned short*>(&vv);
        int col = ((tb ^ (d8 >> 3)) << 3) + tl;
        unsigned short (*dst)[80] = plane ? Glo : Ghi;
        #pragma unroll
        for (int j = 0; j < 8; ++j) dst[d8 + j][col] = vp[j];
    }
    __syncthreads();
    f32x4 acc[2][2];   // [d-frag][f-frag]
    #pragma unroll
    for (int i = 0; i < 2; ++i)
        #pragma unroll
        for (int j = 0; j < 2; ++j) acc[i][j] = (f32x4){0.f, 0.f, 0.f, 0.f};
    #pragma unroll
    for (int kh = 0; kh < 2; ++kh) {
        const int kb = kh * 32 + lg * 8, cb = kb >> 3;
        const int f0r = wcol + lr, f1r = wcol + 16 + lr;
        const int c0 = ((cb ^ ((f0r >> 3) & 7)) << 3), c1 = ((cb ^ ((f1r >> 3) & 7)) << 3);
        bf16x8 bh0 = *reinterpret_cast<const bf16x8*>(&Khi[f0r][c0]);
        bf16x8 bl0 = *reinterpret_cast<const bf16x8*>(&Klo[f0r][c0]);
        bf16x8 bh1 = *reinterpret_cast<const bf16x8*>(&Khi[f1r][c1]);
        bf16x8 bl1 = *reinterpret_cast<const bf16x8*>(&Klo[f1r][c1]);
        #pragma unroll
        for (int di = 0; di < 2; ++di) {
            int dr = wrow + di * 16 + lr;
            int ca = ((cb ^ ((dr >> 3) & 7)) << 3);
            bf16x8 ah = *reinterpret_cast<const bf16x8*>(&Ghi[dr][ca]);
            bf16x8 al = *reinterpret_cast<const bf16x8*>(&Glo[dr][ca]);
            acc[di][0] = mm3(ah, al, bh0, bl0, acc[di][0]);
            acc[di][1] = mm3(ah, al, bh1, bl1, acc[di][1]);
        }
    }
    if (tid < 64) {   // z column sums from kfT tile
        float s = 0.f;
        const int g = (tid >> 3) & 7;
        #pragma unroll
        for (int cb2 = 0; cb2 < 8; ++cb2) {
            int base = ((cb2 ^ g) << 3);
            #pragma unroll
            for (int e = 0; e < 8; ++e)
                s += bf2f(Khi[tid][base + e]) + bf2f(Klo[tid][base + e]);
        }
        zch[(h * NC + c) * FDIM + fh * 64 + tid] = s;
    }
    if (fh == 0) {   // dump Vt tile -> global planes [H][64d][1024t]
        #pragma unroll
        for (int l = 0; l < 4; ++l) {
            int ch = tid + l * 256;
            int plane = ch >> 9, rem = ch & 511;
            int d = rem >> 3, m = rem & 7;
            int g = (d >> 3) & 7;
            const unsigned short (*src)[80] = plane ? Glo : Ghi;
            unsigned short* dst = plane ? Vtlo : Vthi;
            *reinterpret_cast<int4*>(&dst[(size_t)(h * HD + d) * T_LEN + t0 + ((m ^ g) << 3)]) =
                *reinterpret_cast<const int4*>(&src[d][m << 3]);
        }
    }
    float* S = SchT + (size_t)(h * NC + c) * FDIM * HD;
    #pragma unroll
    for (int di = 0; di < 2; ++di)
        #pragma unroll
        for (int fj = 0; fj < 2; ++fj)
            #pragma unroll
            for (int r = 0; r < 4; ++r) {
                int d = wrow + di * 16 + lg * 4 + r;
                int f = fh * 64 + wcol + fj * 16 + lr;
                S[d * FDIM + f] = acc[di][fj][r];   // f in lane -> coalesced
            }
}

// ---------------------------------------------------------------------------
// Kernel 4: exclusive prefix over chunks on [d][f] layout; emits SpreT bf16
// hi/lo planes (packed u32 writes) + zpre f32. Fully coalesced.
// ---------------------------------------------------------------------------
__global__ __launch_bounds__(256) void k_prefix(
    const float* __restrict__ SchT, const float* __restrict__ zch,
    unsigned short* __restrict__ SThi, unsigned short* __restrict__ STlo,
    float* __restrict__ zpre)
{
    const int h = blockIdx.x >> 4;
    const int e = ((blockIdx.x & 15) << 9) + threadIdx.x * 2;   // 0..8190
    const size_t base = (size_t)h * NC * FDIM * HD + e;
    float2 vals[NC];
    #pragma unroll
    for (int c = 0; c < NC; ++c)
        vals[c] = *reinterpret_cast<const float2*>(&SchT[base + (size_t)c * FDIM * HD]);
    float r0 = 0.f, r1 = 0.f;
    #pragma unroll
    for (int c = 0; c < NC; ++c) {
        unsigned short h0 = f2bf(r0), h1 = f2bf(r1);
        unsigned short l0 = f2bf(r0 - bf2f(h0)), l1 = f2bf(r1 - bf2f(h1));
        size_t wi = base + (size_t)c * FDIM * HD;
        *reinterpret_cast<unsigned*>(&SThi[wi]) = (unsigned)h0 | ((unsigned)h1 << 16);
        *reinterpret_cast<unsigned*>(&STlo[wi]) = (unsigned)l0 | ((unsigned)l1 << 16);
        r0 += vals[c].x; r1 += vals[c].y;
    }
    if ((blockIdx.x & 15) == 0 && threadIdx.x < FDIM) {
        const int zb = h * NC * FDIM + threadIdx.x;
        float zv[NC];
        #pragma unroll
        for (int c = 0; c < NC; ++c) zv[c] = zch[zb + c * FDIM];
        float zr = 0.0f;
        #pragma unroll
        for (int c = 0; c < NC; ++c) { zpre[zb + c * FDIM] = zr; zr += zv[c]; }
    }
}

// ---------------------------------------------------------------------------
// Kernel 5: attention core (R9 staged version — measured best).
// ---------------------------------------------------------------------------
__global__ __launch_bounds__(256) void k_attn_mfma(
    const unsigned short* __restrict__ qfhi, const unsigned short* __restrict__ qflo,
    const unsigned short* __restrict__ kfhi, const unsigned short* __restrict__ kflo,
    const unsigned short* __restrict__ SThi, const unsigned short* __restrict__ STlo,
    const unsigned short* __restrict__ Vthi, const unsigned short* __restrict__ Vtlo,
    const float* __restrict__ zpre,
    unsigned short* __restrict__ AThi, unsigned short* __restrict__ ATlo)
{
    const int b = blockIdx.x;
    const int h = b >> 5, c = (b >> 1) & 15, half = b & 1;
    const int tc0 = c * TC;
    const int tq0 = tc0 + half * 32;
    const int tid = threadIdx.x, lane = tid & 63, wid = tid >> 6;
    const int wrow = (wid >> 1) * 16, wcol = (wid & 1) * 32;
    const int lr = lane & 15, lg = lane >> 4;

    __shared__ __align__(16) unsigned short T0[32][80], T1[32][80];  // qf -> A
    __shared__ __align__(16) unsigned short T2[64][80], T3[64][80];  // kf -> Vt
    __shared__ __align__(16) unsigned short T4[64][80], T5[64][80];  // SpreT [d][f]
    __shared__ unsigned short zhi[FDIM], zlo[FDIM];
    __shared__ float nrm_part[2][32], nrm[32];

    if (tid < FDIM) {
        float zv = zpre[(h * NC + c) * FDIM + tid];
        unsigned short zh = f2bf(zv);
        zhi[tid] = zh; zlo[tid] = f2bf(zv - bf2f(zh));
    }

    f32x4 accA[2], accC[2], accN;
    accA[0] = accA[1] = accC[0] = accC[1] = accN = (f32x4){0.f, 0.f, 0.f, 0.f};

    for (int f0 = 0; f0 < FDIM; f0 += 64) {
        {   // qf: 32 rows
            int row = tid >> 3, sg = (tid & 7) * 8;
            size_t qo = (size_t)(h * T_LEN + tq0 + row) * FDIM + f0 + sg;
            *reinterpret_cast<int4*>(&T0[row][sg]) = *reinterpret_cast<const int4*>(&qfhi[qo]);
            *reinterpret_cast<int4*>(&T1[row][sg]) = *reinterpret_cast<const int4*>(&qflo[qo]);
        }
        #pragma unroll
        for (int l = 0; l < 2; ++l) {   // kf: 64 rows
            int ch = tid + l * 256;
            int row = ch >> 3, sg = (ch & 7) * 8;
            size_t ko = (size_t)(h * T_LEN + tc0 + row) * FDIM + f0 + sg;
            *reinterpret_cast<int4*>(&T2[row][sg]) = *reinterpret_cast<const int4*>(&kfhi[ko]);
            *reinterpret_cast<int4*>(&T3[row][sg]) = *reinterpret_cast<const int4*>(&kflo[ko]);
        }
        #pragma unroll
        for (int l = 0; l < 2; ++l) {   // SpreT [d][f-slice]: pure int4 copy
            int ch = tid + l * 256;
            int row = ch >> 3, sg = (ch & 7) * 8;
            size_t so = (size_t)(h * NC + c) * FDIM * HD + (size_t)row * FDIM + f0 + sg;
            *reinterpret_cast<int4*>(&T4[row][sg]) = *reinterpret_cast<const int4*>(&SThi[so]);
            *reinterpret_cast<int4*>(&T5[row][sg]) = *reinterpret_cast<const int4*>(&STlo[so]);
        }
        __syncthreads();
        #pragma unroll
        for (int kh = 0; kh < 2; ++kh) {
            const int kb = kh * 32 + lg * 8;
            bf16x8 qh = LD8(T0, wrow + lr, kb), ql = LD8(T1, wrow + lr, kb);
            bf16x8 kh0 = LD8(T2, wcol + lr, kb),      kh1 = LD8(T2, wcol + 16 + lr, kb);
            bf16x8 kl0 = LD8(T3, wcol + lr, kb),      kl1 = LD8(T3, wcol + 16 + lr, kb);
            bf16x8 sh0 = LD8(T4, wcol + lr, kb),      sh1 = LD8(T4, wcol + 16 + lr, kb);
            bf16x8 sl0 = LD8(T5, wcol + lr, kb),      sl1 = LD8(T5, wcol + 16 + lr, kb);
            accA[0] = mm3(qh, ql, kh0, kl0, accA[0]);
            accA[1] = mm3(qh, ql, kh1, kl1, accA[1]);
            accC[0] = mm3(qh, ql, sh0, sl0, accC[0]);
            accC[1] = mm3(qh, ql, sh1, sl1, accC[1]);
            bf16x8 zh8, zl8;
            #pragma unroll
            for (int j = 0; j < 8; ++j) {
                zh8[j] = (short)zhi[f0 + kb + j];
                zl8[j] = (short)zlo[f0 + kb + j];
            }
            accN = mm3(qh, ql, zh8, zl8, accN);
        }
        __syncthreads();
    }

    // phase 2: mask + rowsum + A -> T0/T1 ; Vt planes -> T2/T3 (int4 copies)
    #pragma unroll
    for (int r = 0; r < 4; ++r) {
        int rowl = wrow + lg * 4 + r;
        int rowc = half * 32 + rowl;
        float rs = 0.f;
        #pragma unroll
        for (int j = 0; j < 2; ++j) {
            int col = wcol + j * 16 + lr;
            float vA = (col <= rowc) ? accA[j][r] : 0.f;
            rs += vA;
            unsigned short hv = f2bf(vA);
            T0[rowl][col] = hv;
            T1[rowl][col] = f2bf(vA - bf2f(hv));
        }
        #pragma unroll
        for (int off = 1; off < 16; off <<= 1) rs += __shfl_xor(rs, off, 64);
        if (lr == 0) {
            if ((wid & 1) == 0) nrm_part[0][rowl] = rs + accN[r];
            else                nrm_part[1][rowl] = rs;
        }
    }
    #pragma unroll
    for (int l = 0; l < 4; ++l) {
        int ch = tid + l * 256;
        int plane = ch >> 9, rem = ch & 511;
        int row = rem >> 3, sg = (rem & 7) * 8;
        size_t vo = (size_t)(h * HD + row) * T_LEN + tc0 + sg;
        const unsigned short* src = plane ? Vtlo : Vthi;
        unsigned short (*dst)[80] = plane ? T3 : T2;
        *reinterpret_cast<int4*>(&dst[row][sg]) = *reinterpret_cast<const int4*>(&src[vo]);
    }
    __syncthreads();
    if (tid < 32) nrm[tid] = fmaxf(nrm_part[0][tid] + nrm_part[1][tid], 1e-6f);

    // phase 3: accC += A_masked @ V  (B-op = Vt [d][t], plain reads)
    #pragma unroll
    for (int kh = 0; kh < 2; ++kh) {
        const int kb = kh * 32 + lg * 8;
        bf16x8 ah = LD8(T0, wrow + lr, kb), al = LD8(T1, wrow + lr, kb);
        bf16x8 vh0 = LD8(T2, wcol + lr, kb),      vh1 = LD8(T2, wcol + 16 + lr, kb);
        bf16x8 vl0 = LD8(T3, wcol + lr, kb),      vl1 = LD8(T3, wcol + 16 + lr, kb);
        accC[0] = mm3(ah, al, vh0, vl0, accC[0]);
        accC[1] = mm3(ah, al, vh1, vl1, accC[1]);
    }
    __syncthreads();

    #pragma unroll
    for (int j = 0; j < 2; ++j)
        #pragma unroll
        for (int r = 0; r < 4; ++r) {
            int rowl = wrow + lg * 4 + r;
            int col = wcol + j * 16 + lr;
            float o = accC[j][r] / nrm[rowl];
            unsigned short hv = f2bf(o);
            size_t oi = (size_t)(tq0 + rowl) * EMB + h * HD + col;
            AThi[oi] = hv; ATlo[oi] = f2bf(o - bf2f(hv));
        }
}

// ---------------------------------------------------------------------------
// Workspace ~24.1 MB. Overlays (producer/consumer order audited):
//   AThi/ATlo in Xhi/Xlo  (X read only by k_qkv; AT written by k_attn)
//   Vthi/Vtlo in Whi/Wlo  (W read only by k_qkv; Vt written by k_chunk)
// ---------------------------------------------------------------------------
extern "C" void kernel_launch(void* const* d_in, const int* in_sizes, int n_in,
                              void* d_out, int out_size, void* d_ws, size_t ws_size,
                              hipStream_t stream) {
    const float* x         = (const float*)d_in[0];
    const float* qkv_w     = (const float*)d_in[1];
    const float* qkv_b     = (const float*)d_in[2];
    const float* out_w     = (const float*)d_in[3];
    const float* out_b     = (const float*)d_in[4];
    const float* omega     = (const float*)d_in[5];
    const float* poly_proj = (const float*)d_in[6];
    float* out = (float*)d_out;

    unsigned short* Xhi  = (unsigned short*)d_ws;           // 524288
    unsigned short* Xlo  = Xhi + 524288;
    unsigned short* Whi  = Xlo + 524288;                    // 786432
    unsigned short* Wlo  = Whi + 786432;
    unsigned short* Ohi  = Wlo + 786432;                    // 262144
    unsigned short* Olo  = Ohi + 262144;
    unsigned short* Vhi  = Olo + 262144;                    // 524288
    unsigned short* Vlo  = Vhi + 524288;
    unsigned short* qfhi = Vlo + 524288;                    // 1048576 each
    unsigned short* qflo = qfhi + 1048576;
    unsigned short* kfhi = qflo + 1048576;
    unsigned short* kflo = kfhi + 1048576;
    float* SchT = (float*)(kflo + 1048576);                 // 1048576 f32
    unsigned short* SThi = (unsigned short*)(SchT + 1048576); // 1048576 each
    unsigned short* STlo = SThi + 1048576;
    float* zch  = (float*)(STlo + 1048576);                 // 16384
    float* zpre = zch + 16384;                              // 16384
    unsigned short* AThi = Xhi;                             // overlay
    unsigned short* ATlo = Xlo;                             // overlay
    unsigned short* Vthi = Whi;                             // overlay (1MB in W's 3MB)
    unsigned short* Vtlo = Whi + 524288;                    // overlay

    k_cvt<<<1536, 256, 0, stream>>>(x, qkv_w, out_w, Xhi, Xlo, Whi, Wlo, Ohi, Olo);
    k_qkv_mfma<<<dim3(24, 8), 512, 0, stream>>>(Xhi, Xlo, Whi, Wlo, qkv_b,
                                                poly_proj, omega, Vhi, Vlo,
                                                qfhi, qflo, kfhi, kflo);
    k_chunk_kv<<<256, 256, 0, stream>>>(kfhi, kflo, Vhi, Vlo, SchT, zch, Vthi, Vtlo);
    k_prefix<<<128, 256, 0, stream>>>(SchT, zch, SThi, STlo, zpre);
    k_attn_mfma<<<NH * NC * 2, 256, 0, stream>>>(qfhi, qflo, kfhi, kflo, SThi, STlo,
                                                 Vthi, Vtlo, zpre, AThi, ATlo);
    k_out_mfma<<<dim3(8, 16), 256, 0, stream>>>(AThi, ATlo, Ohi, Olo, out_b, out);
}

// Round 13
// 111.740 us; speedup vs baseline: 1.0328x; 1.0328x over previous
//
#include <hip/hip_runtime.h>

#define T_LEN 1024
#define EMB   512
#define NH    8
#define HD    64
#define PDIM  32
#define MDIM  4
#define FDIM  128   // PDIM*MDIM
#define TC    64    // chunk length
#define NC    16    // T_LEN/TC

typedef __attribute__((ext_vector_type(8))) short bf16x8;
typedef __attribute__((ext_vector_type(4))) float f32x4;

__device__ __forceinline__ unsigned short f2bf(float f) {
    unsigned u = __float_as_uint(f);
    unsigned r = u + 0x7fffu + ((u >> 16) & 1u);   // RNE
    return (unsigned short)(r >> 16);
}
__device__ __forceinline__ float bf2f(unsigned short h) {
    return __uint_as_float(((unsigned)h) << 16);
}
__device__ __forceinline__ void split4(float4 v, ushort4& h4, ushort4& l4) {
    h4.x = f2bf(v.x); l4.x = f2bf(v.x - bf2f(h4.x));
    h4.y = f2bf(v.y); l4.y = f2bf(v.y - bf2f(h4.y));
    h4.z = f2bf(v.z); l4.z = f2bf(v.z - bf2f(h4.z));
    h4.w = f2bf(v.w); l4.w = f2bf(v.w - bf2f(h4.w));
}
// split-bf16 product: (ah+al)*(bh+bl) ~= ah*bh + ah*bl + al*bh
__device__ __forceinline__ f32x4 mm3(bf16x8 ah, bf16x8 al, bf16x8 bh, bf16x8 bl, f32x4 acc) {
    acc = __builtin_amdgcn_mfma_f32_16x16x32_bf16(ah, bh, acc, 0, 0, 0);
    acc = __builtin_amdgcn_mfma_f32_16x16x32_bf16(ah, bl, acc, 0, 0, 0);
    acc = __builtin_amdgcn_mfma_f32_16x16x32_bf16(al, bh, acc, 0, 0, 0);
    return acc;
}
#define LD8(TILE, ROW, KB) (*reinterpret_cast<const bf16x8*>(&TILE[ROW][KB]))

// ---------------------------------------------------------------------------
// Kernel 0: pre-split f32 -> bf16 hi/lo planes for x, qkv_w, out_w.
// ---------------------------------------------------------------------------
__global__ __launch_bounds__(256) void k_cvt(
    const float* __restrict__ X, const float* __restrict__ Wq,
    const float* __restrict__ Wo,
    unsigned short* __restrict__ Xhi, unsigned short* __restrict__ Xlo,
    unsigned short* __restrict__ Whi, unsigned short* __restrict__ Wlo,
    unsigned short* __restrict__ Ohi, unsigned short* __restrict__ Olo)
{
    int i = (blockIdx.x * 256 + threadIdx.x) * 4;
    const float* src; unsigned short *dh, *dl; int off;
    if (i < 524288)       { src = X;  dh = Xhi; dl = Xlo; off = i; }
    else if (i < 1310720) { src = Wq; dh = Whi; dl = Wlo; off = i - 524288; }
    else                  { src = Wo; dh = Ohi; dl = Olo; off = i - 1310720; }
    float4 v = *reinterpret_cast<const float4*>(&src[off]);
    ushort4 h4, l4; split4(v, h4, l4);
    *reinterpret_cast<ushort4*>(&dh[off]) = h4;
    *reinterpret_cast<ushort4*>(&dl[off]) = l4;
}

// ---------------------------------------------------------------------------
// Kernel 1: qkv GEMM (pre-split operands, pure int4 staging) + FUSED features.
// ---------------------------------------------------------------------------
__global__ __launch_bounds__(256) void k_qkv_mfma(
    const unsigned short* __restrict__ Xhi, const unsigned short* __restrict__ Xlo,
    const unsigned short* __restrict__ Whi, const unsigned short* __restrict__ Wlo,
    const float* __restrict__ bias,
    const float* __restrict__ poly_proj, const float* __restrict__ omega,
    unsigned short* __restrict__ Vhi, unsigned short* __restrict__ Vlo,
    unsigned short* __restrict__ qfhi, unsigned short* __restrict__ qflo,
    unsigned short* __restrict__ kfhi, unsigned short* __restrict__ kflo)
{
    const int j0 = blockIdx.x * 64;   // N=1536
    const int t0 = blockIdx.y * 64;   // M=1024
    __shared__ __align__(16) unsigned short Ahi[64][80], Alo[64][80],
                                            Bhi[64][80], Blo[64][80];
    __shared__ float poly_s[64][33];
    __shared__ float prf_s[64][5];
    __shared__ float nrm2[2][64];
    const int tid = threadIdx.x, lane = tid & 63, wid = tid >> 6;
    const int wrow = (wid >> 1) * 32, wcol = (wid & 1) * 32;
    const int lr = lane & 15, lg = lane >> 4;
    f32x4 acc[2][2];
    #pragma unroll
    for (int i = 0; i < 2; ++i)
        #pragma unroll
        for (int j = 0; j < 2; ++j) acc[i][j] = (f32x4){0.f, 0.f, 0.f, 0.f};

    for (int k0 = 0; k0 < 512; k0 += 64) {
        #pragma unroll
        for (int l = 0; l < 2; ++l) {
            int ch = tid + l * 256;
            int row = ch >> 3, sg = (ch & 7) * 8;
            size_t ao = (size_t)(t0 + row) * 512 + k0 + sg;
            size_t bo = (size_t)(j0 + row) * 512 + k0 + sg;
            *reinterpret_cast<int4*>(&Ahi[row][sg]) = *reinterpret_cast<const int4*>(&Xhi[ao]);
            *reinterpret_cast<int4*>(&Alo[row][sg]) = *reinterpret_cast<const int4*>(&Xlo[ao]);
            *reinterpret_cast<int4*>(&Bhi[row][sg]) = *reinterpret_cast<const int4*>(&Whi[bo]);
            *reinterpret_cast<int4*>(&Blo[row][sg]) = *reinterpret_cast<const int4*>(&Wlo[bo]);
        }
        __syncthreads();
        #pragma unroll
        for (int kh = 0; kh < 2; ++kh) {
            const int kb = kh * 32 + lg * 8;
            bf16x8 ah0 = LD8(Ahi, wrow + lr, kb),      ah1 = LD8(Ahi, wrow + 16 + lr, kb);
            bf16x8 al0 = LD8(Alo, wrow + lr, kb),      al1 = LD8(Alo, wrow + 16 + lr, kb);
            bf16x8 bh0 = LD8(Bhi, wcol + lr, kb),      bh1 = LD8(Bhi, wcol + 16 + lr, kb);
            bf16x8 bl0 = LD8(Blo, wcol + lr, kb),      bl1 = LD8(Blo, wcol + 16 + lr, kb);
            acc[0][0] = mm3(ah0, al0, bh0, bl0, acc[0][0]);
            acc[0][1] = mm3(ah0, al0, bh1, bl1, acc[0][1]);
            acc[1][0] = mm3(ah1, al1, bh0, bl0, acc[1][0]);
            acc[1][1] = mm3(ah1, al1, bh1, bl1, acc[1][1]);
        }
        __syncthreads();
    }
    const int which = j0 >> 9;
    const int h = (j0 & 511) >> 6;

    if (which == 2) {   // v output as bf16 hi/lo planes (coalesced)
        #pragma unroll
        for (int i = 0; i < 2; ++i)
            #pragma unroll
            for (int j = 0; j < 2; ++j)
                #pragma unroll
                for (int r = 0; r < 4; ++r) {
                    int row = wrow + i * 16 + lg * 4 + r;
                    int col = wcol + j * 16 + lr;
                    float val = acc[i][j][r] + bias[j0 + col];
                    unsigned short hv = f2bf(val);
                    size_t vi = (size_t)(h * T_LEN + t0 + row) * HD + col;
                    Vhi[vi] = hv; Vlo[vi] = f2bf(val - bf2f(hv));
                }
        return;
    }

    // ---- fused features ----
    #pragma unroll
    for (int i = 0; i < 2; ++i) {
        #pragma unroll
        for (int r = 0; r < 4; ++r) {
            int row = wrow + i * 16 + lg * 4 + r;
            float ss = 0.f;
            #pragma unroll
            for (int j = 0; j < 2; ++j) {
                int col = wcol + j * 16 + lr;
                float zv = acc[i][j][r] + bias[j0 + col];
                ss = fmaf(zv, zv, ss);
                unsigned short hv = f2bf(zv);
                Ahi[row][col] = hv;
                Alo[row][col] = f2bf(zv - bf2f(hv));
            }
            ss += __shfl_xor(ss, 1, 64);
            ss += __shfl_xor(ss, 2, 64);
            ss += __shfl_xor(ss, 4, 64);
            ss += __shfl_xor(ss, 8, 64);
            if (lr == 0) nrm2[wid & 1][row] = ss;
        }
    }
    {   // Bp = [P^T | om^T | 0pad] (48 x 64)
        const float* P = poly_proj + (size_t)h * 64 * 32;   // [d][p]
        int d = tid >> 2, p8 = (tid & 3) * 8;
        #pragma unroll
        for (int e = 0; e < 8; ++e) {
            float pv = P[d * 32 + p8 + e];
            unsigned short hv = f2bf(pv);
            Bhi[p8 + e][d] = hv;
            Blo[p8 + e][d] = f2bf(pv - bf2f(hv));
        }
        if (tid < 64) {
            const float* Om = omega + (size_t)h * 64 * 4;   // [d][m]
            float4 om = *reinterpret_cast<const float4*>(&Om[tid * 4]);
            float oa[4] = {om.x, om.y, om.z, om.w};
            #pragma unroll
            for (int m = 0; m < 4; ++m) {
                unsigned short hv = f2bf(oa[m]);
                Bhi[32 + m][tid] = hv;
                Blo[32 + m][tid] = f2bf(oa[m] - bf2f(hv));
            }
        }
        for (int rr = tid; rr < 12 * 64; rr += 256) {
            int row = 36 + (rr >> 6), dd = rr & 63;
            Bhi[row][dd] = 0; Blo[row][dd] = 0;
        }
    }
    __syncthreads();
    const int mrow = wid * 16;
    f32x4 g[3];
    g[0] = g[1] = g[2] = (f32x4){0.f, 0.f, 0.f, 0.f};
    #pragma unroll
    for (int kh = 0; kh < 2; ++kh) {
        const int kb = kh * 32 + lg * 8;
        bf16x8 ah = LD8(Ahi, mrow + lr, kb), al = LD8(Alo, mrow + lr, kb);
        #pragma unroll
        for (int j = 0; j < 3; ++j) {
            bf16x8 bh = LD8(Bhi, j * 16 + lr, kb), bl = LD8(Blo, j * 16 + lr, kb);
            g[j] = mm3(ah, al, bh, bl, g[j]);
        }
    }
    const float S_NODE = (float)(1.0 / 2.000001);
    const float SQRT2S = sqrtf(2.0f * S_NODE);
    #pragma unroll
    for (int r = 0; r < 4; ++r) {
        int row = mrow + lg * 4 + r;
        float rn = 1.0f / fmaxf(sqrtf(nrm2[0][row] + nrm2[1][row]), 1e-12f);
        #pragma unroll
        for (int j = 0; j < 3; ++j) {
            float gv = g[j][r] * rn;
            if (j < 2) poly_s[row][j * 16 + lr] = gv * gv;
            else if (lr < 4) {
                float arg = fminf(fmaxf(fmaf(gv, SQRT2S, -S_NODE), -20.0f), 20.0f);
                prf_s[row][lr] = expf(arg) * 0.5f;
            }
        }
    }
    {
        int row = mrow + (lane >> 2), fq = lane & 3;
        float pr[8], pf[4];
        #pragma unroll
        for (int e = 0; e < 8; ++e) pr[e] = poly_s[row][fq * 8 + e];
        #pragma unroll
        for (int m = 0; m < 4; ++m) pf[m] = prf_s[row][m];
        int4 hi4[4], lo4[4];
        unsigned short* hp = reinterpret_cast<unsigned short*>(hi4);
        unsigned short* lp = reinterpret_cast<unsigned short*>(lo4);
        #pragma unroll
        for (int e = 0; e < 8; ++e)
            #pragma unroll
            for (int m = 0; m < 4; ++m) {
                float val = pr[e] * pf[m];
                unsigned short hv = f2bf(val);
                hp[e * 4 + m] = hv;
                lp[e * 4 + m] = f2bf(val - bf2f(hv));
            }
        unsigned short* dhi = (which == 0) ? qfhi : kfhi;
        unsigned short* dlo = (which == 0) ? qflo : kflo;
        size_t base = (size_t)(h * T_LEN + t0 + row) * FDIM + fq * 32;
        #pragma unroll
        for (int s = 0; s < 4; ++s) {
            *reinterpret_cast<int4*>(&dhi[base + s * 8]) = hi4[s];
            *reinterpret_cast<int4*>(&dlo[base + s * 8]) = lo4[s];
        }
    }
}

// ---------------------------------------------------------------------------
// Kernel 6: y = attn @ out_w^T + out_b. All operands pre-split: int4 staging.
// ---------------------------------------------------------------------------
__global__ __launch_bounds__(256) void k_out_mfma(
    const unsigned short* __restrict__ AThi, const unsigned short* __restrict__ ATlo,
    const unsigned short* __restrict__ Ohi, const unsigned short* __restrict__ Olo,
    const float* __restrict__ bias, float* __restrict__ Y)
{
    const int j0 = blockIdx.x * 64;
    const int t0 = blockIdx.y * 64;
    __shared__ __align__(16) unsigned short Ahi[64][80], Alo[64][80],
                                            Bhi[64][80], Blo[64][80];
    const int tid = threadIdx.x, lane = tid & 63, wid = tid >> 6;
    const int wrow = (wid >> 1) * 32, wcol = (wid & 1) * 32;
    const int lr = lane & 15, lg = lane >> 4;
    f32x4 acc[2][2];
    #pragma unroll
    for (int i = 0; i < 2; ++i)
        #pragma unroll
        for (int j = 0; j < 2; ++j) acc[i][j] = (f32x4){0.f, 0.f, 0.f, 0.f};

    for (int k0 = 0; k0 < 512; k0 += 64) {
        #pragma unroll
        for (int l = 0; l < 2; ++l) {
            int ch = tid + l * 256;
            int row = ch >> 3, sg = (ch & 7) * 8;
            size_t ao = (size_t)(t0 + row) * 512 + k0 + sg;
            size_t bo = (size_t)(j0 + row) * 512 + k0 + sg;
            *reinterpret_cast<int4*>(&Ahi[row][sg]) = *reinterpret_cast<const int4*>(&AThi[ao]);
            *reinterpret_cast<int4*>(&Alo[row][sg]) = *reinterpret_cast<const int4*>(&ATlo[ao]);
            *reinterpret_cast<int4*>(&Bhi[row][sg]) = *reinterpret_cast<const int4*>(&Ohi[bo]);
            *reinterpret_cast<int4*>(&Blo[row][sg]) = *reinterpret_cast<const int4*>(&Olo[bo]);
        }
        __syncthreads();
        #pragma unroll
        for (int kh = 0; kh < 2; ++kh) {
            const int kb = kh * 32 + lg * 8;
            bf16x8 ah0 = LD8(Ahi, wrow + lr, kb),      ah1 = LD8(Ahi, wrow + 16 + lr, kb);
            bf16x8 al0 = LD8(Alo, wrow + lr, kb),      al1 = LD8(Alo, wrow + 16 + lr, kb);
            bf16x8 bh0 = LD8(Bhi, wcol + lr, kb),      bh1 = LD8(Bhi, wcol + 16 + lr, kb);
            bf16x8 bl0 = LD8(Blo, wcol + lr, kb),      bl1 = LD8(Blo, wcol + 16 + lr, kb);
            acc[0][0] = mm3(ah0, al0, bh0, bl0, acc[0][0]);
            acc[0][1] = mm3(ah0, al0, bh1, bl1, acc[0][1]);
            acc[1][0] = mm3(ah1, al1, bh0, bl0, acc[1][0]);
            acc[1][1] = mm3(ah1, al1, bh1, bl1, acc[1][1]);
        }
        __syncthreads();
    }
    #pragma unroll
    for (int i = 0; i < 2; ++i)
        #pragma unroll
        for (int j = 0; j < 2; ++j)
            #pragma unroll
            for (int r = 0; r < 4; ++r) {
                int row = wrow + i * 16 + lg * 4 + r;
                int col = wcol + j * 16 + lr;
                Y[(size_t)(t0 + row) * EMB + j0 + col] = acc[i][j][r] + bias[j0 + col];
            }
}

// ---------------------------------------------------------------------------
// Kernel 3: per-chunk SchT[d][f] = (V^T kf) via MFMA; dumps Vt planes (fh==0)
// and z column sums.
// ---------------------------------------------------------------------------
__global__ __launch_bounds__(256) void k_chunk_kv(
    const unsigned short* __restrict__ kfhi, const unsigned short* __restrict__ kflo,
    const unsigned short* __restrict__ Vhi, const unsigned short* __restrict__ Vlo,
    float* __restrict__ SchT, float* __restrict__ zch,
    unsigned short* __restrict__ Vthi, unsigned short* __restrict__ Vtlo)
{
    const int b = blockIdx.x;
    const int fh = b & 1, hc = b >> 1, h = hc >> 4, c = hc & 15;
    const int t0 = c * TC;
    const int tid = threadIdx.x, lane = tid & 63, wid = tid >> 6;
    const int wrow = (wid >> 1) * 32, wcol = (wid & 1) * 32;
    const int lr = lane & 15, lg = lane >> 4;
    __shared__ __align__(16) unsigned short Khi[64][80], Klo[64][80],   // kfT
                                            Ghi[64][80], Glo[64][80];   // Vt
    #pragma unroll
    for (int l = 0; l < 2; ++l) {   // kfT: transpose from kf (swizzled)
        int ch = tid + l * 256;
        int t = ch >> 3, f8 = (ch & 7) * 8;
        int tb = t >> 3, tl = t & 7, m = f8 >> 3;
        size_t ko = (size_t)((h << 10) + t0 + t) * FDIM + fh * 64 + f8;
        int4 hv = *reinterpret_cast<const int4*>(&kfhi[ko]);
        int4 lv = *reinterpret_cast<const int4*>(&kflo[ko]);
        const unsigned short* hp = reinterpret_cast<const unsigned short*>(&hv);
        const unsigned short* lp = reinterpret_cast<const unsigned short*>(&lv);
        int col = ((tb ^ m) << 3) + tl;
        #pragma unroll
        for (int j = 0; j < 8; ++j) {
            Khi[f8 + j][col] = hp[j];
            Klo[f8 + j][col] = lp[j];
        }
    }
    #pragma unroll
    for (int l = 0; l < 4; ++l) {   // Vt: transpose from V planes (swizzled)
        int ch = tid + l * 256;     // 0..1023
        int plane = ch >> 9, rem = ch & 511;
        int t = rem >> 3, d8 = (rem & 7) * 8;
        int tb = t >> 3, tl = t & 7;
        const unsigned short* src = plane ? Vlo : Vhi;
        int4 vv = *reinterpret_cast<const int4*>(&src[(size_t)((h << 10) + t0 + t) * HD + d8]);
        const unsigned short* vp = reinterpret_cast<const unsigned short*>(&vv);
        int col = ((tb ^ (d8 >> 3)) << 3) + tl;
        unsigned short (*dst)[80] = plane ? Glo : Ghi;
        #pragma unroll
        for (int j = 0; j < 8; ++j) dst[d8 + j][col] = vp[j];
    }
    __syncthreads();
    f32x4 acc[2][2];   // [d-frag][f-frag]
    #pragma unroll
    for (int i = 0; i < 2; ++i)
        #pragma unroll
        for (int j = 0; j < 2; ++j) acc[i][j] = (f32x4){0.f, 0.f, 0.f, 0.f};
    #pragma unroll
    for (int kh = 0; kh < 2; ++kh) {
        const int kb = kh * 32 + lg * 8, cb = kb >> 3;
        const int f0r = wcol + lr, f1r = wcol + 16 + lr;
        const int c0 = ((cb ^ ((f0r >> 3) & 7)) << 3), c1 = ((cb ^ ((f1r >> 3) & 7)) << 3);
        bf16x8 bh0 = *reinterpret_cast<const bf16x8*>(&Khi[f0r][c0]);
        bf16x8 bl0 = *reinterpret_cast<const bf16x8*>(&Klo[f0r][c0]);
        bf16x8 bh1 = *reinterpret_cast<const bf16x8*>(&Khi[f1r][c1]);
        bf16x8 bl1 = *reinterpret_cast<const bf16x8*>(&Klo[f1r][c1]);
        #pragma unroll
        for (int di = 0; di < 2; ++di) {
            int dr = wrow + di * 16 + lr;
            int ca = ((cb ^ ((dr >> 3) & 7)) << 3);
            bf16x8 ah = *reinterpret_cast<const bf16x8*>(&Ghi[dr][ca]);
            bf16x8 al = *reinterpret_cast<const bf16x8*>(&Glo[dr][ca]);
            acc[di][0] = mm3(ah, al, bh0, bl0, acc[di][0]);
            acc[di][1] = mm3(ah, al, bh1, bl1, acc[di][1]);
        }
    }
    if (tid < 64) {   // z column sums from kfT tile
        float s = 0.f;
        const int g = (tid >> 3) & 7;
        #pragma unroll
        for (int cb2 = 0; cb2 < 8; ++cb2) {
            int base = ((cb2 ^ g) << 3);
            #pragma unroll
            for (int e = 0; e < 8; ++e)
                s += bf2f(Khi[tid][base + e]) + bf2f(Klo[tid][base + e]);
        }
        zch[(h * NC + c) * FDIM + fh * 64 + tid] = s;
    }
    if (fh == 0) {   // dump Vt tile -> global planes [H][64d][1024t]
        #pragma unroll
        for (int l = 0; l < 4; ++l) {
            int ch = tid + l * 256;
            int plane = ch >> 9, rem = ch & 511;
            int d = rem >> 3, m = rem & 7;
            int g = (d >> 3) & 7;
            const unsigned short (*src)[80] = plane ? Glo : Ghi;
            unsigned short* dst = plane ? Vtlo : Vthi;
            *reinterpret_cast<int4*>(&dst[(size_t)(h * HD + d) * T_LEN + t0 + ((m ^ g) << 3)]) =
                *reinterpret_cast<const int4*>(&src[d][m << 3]);
        }
    }
    float* S = SchT + (size_t)(h * NC + c) * FDIM * HD;
    #pragma unroll
    for (int di = 0; di < 2; ++di)
        #pragma unroll
        for (int fj = 0; fj < 2; ++fj)
            #pragma unroll
            for (int r = 0; r < 4; ++r) {
                int d = wrow + di * 16 + lg * 4 + r;
                int f = fh * 64 + wcol + fj * 16 + lr;
                S[d * FDIM + f] = acc[di][fj][r];   // f in lane -> coalesced
            }
}

// ---------------------------------------------------------------------------
// Kernel 4: exclusive prefix over chunks on [d][f] layout; emits SpreT bf16
// hi/lo planes (packed u32 writes) + zpre f32. Fully coalesced.
// ---------------------------------------------------------------------------
__global__ __launch_bounds__(256) void k_prefix(
    const float* __restrict__ SchT, const float* __restrict__ zch,
    unsigned short* __restrict__ SThi, unsigned short* __restrict__ STlo,
    float* __restrict__ zpre)
{
    const int h = blockIdx.x >> 4;
    const int e = ((blockIdx.x & 15) << 9) + threadIdx.x * 2;   // 0..8190
    const size_t base = (size_t)h * NC * FDIM * HD + e;
    float2 vals[NC];
    #pragma unroll
    for (int c = 0; c < NC; ++c)
        vals[c] = *reinterpret_cast<const float2*>(&SchT[base + (size_t)c * FDIM * HD]);
    float r0 = 0.f, r1 = 0.f;
    #pragma unroll
    for (int c = 0; c < NC; ++c) {
        unsigned short h0 = f2bf(r0), h1 = f2bf(r1);
        unsigned short l0 = f2bf(r0 - bf2f(h0)), l1 = f2bf(r1 - bf2f(h1));
        size_t wi = base + (size_t)c * FDIM * HD;
        *reinterpret_cast<unsigned*>(&SThi[wi]) = (unsigned)h0 | ((unsigned)h1 << 16);
        *reinterpret_cast<unsigned*>(&STlo[wi]) = (unsigned)l0 | ((unsigned)l1 << 16);
        r0 += vals[c].x; r1 += vals[c].y;
    }
    if ((blockIdx.x & 15) == 0 && threadIdx.x < FDIM) {
        const int zb = h * NC * FDIM + threadIdx.x;
        float zv[NC];
        #pragma unroll
        for (int c = 0; c < NC; ++c) zv[c] = zch[zb + c * FDIM];
        float zr = 0.0f;
        #pragma unroll
        for (int c = 0; c < NC; ++c) { zpre[zb + c * FDIM] = zr; zr += zv[c]; }
    }
}

// ---------------------------------------------------------------------------
// Kernel 5: attention core (R9 staged version — measured best).
// ---------------------------------------------------------------------------
__global__ __launch_bounds__(256) void k_attn_mfma(
    const unsigned short* __restrict__ qfhi, const unsigned short* __restrict__ qflo,
    const unsigned short* __restrict__ kfhi, const unsigned short* __restrict__ kflo,
    const unsigned short* __restrict__ SThi, const unsigned short* __restrict__ STlo,
    const unsigned short* __restrict__ Vthi, const unsigned short* __restrict__ Vtlo,
    const float* __restrict__ zpre,
    unsigned short* __restrict__ AThi, unsigned short* __restrict__ ATlo)
{
    const int b = blockIdx.x;
    const int h = b >> 5, c = (b >> 1) & 15, half = b & 1;
    const int tc0 = c * TC;
    const int tq0 = tc0 + half * 32;
    const int tid = threadIdx.x, lane = tid & 63, wid = tid >> 6;
    const int wrow = (wid >> 1) * 16, wcol = (wid & 1) * 32;
    const int lr = lane & 15, lg = lane >> 4;

    __shared__ __align__(16) unsigned short T0[32][80], T1[32][80];  // qf -> A
    __shared__ __align__(16) unsigned short T2[64][80], T3[64][80];  // kf -> Vt
    __shared__ __align__(16) unsigned short T4[64][80], T5[64][80];  // SpreT [d][f]
    __shared__ unsigned short zhi[FDIM], zlo[FDIM];
    __shared__ float nrm_part[2][32], nrm[32];

    if (tid < FDIM) {
        float zv = zpre[(h * NC + c) * FDIM + tid];
        unsigned short zh = f2bf(zv);
        zhi[tid] = zh; zlo[tid] = f2bf(zv - bf2f(zh));
    }

    f32x4 accA[2], accC[2], accN;
    accA[0] = accA[1] = accC[0] = accC[1] = accN = (f32x4){0.f, 0.f, 0.f, 0.f};

    for (int f0 = 0; f0 < FDIM; f0 += 64) {
        {   // qf: 32 rows
            int row = tid >> 3, sg = (tid & 7) * 8;
            size_t qo = (size_t)(h * T_LEN + tq0 + row) * FDIM + f0 + sg;
            *reinterpret_cast<int4*>(&T0[row][sg]) = *reinterpret_cast<const int4*>(&qfhi[qo]);
            *reinterpret_cast<int4*>(&T1[row][sg]) = *reinterpret_cast<const int4*>(&qflo[qo]);
        }
        #pragma unroll
        for (int l = 0; l < 2; ++l) {   // kf: 64 rows
            int ch = tid + l * 256;
            int row = ch >> 3, sg = (ch & 7) * 8;
            size_t ko = (size_t)(h * T_LEN + tc0 + row) * FDIM + f0 + sg;
            *reinterpret_cast<int4*>(&T2[row][sg]) = *reinterpret_cast<const int4*>(&kfhi[ko]);
            *reinterpret_cast<int4*>(&T3[row][sg]) = *reinterpret_cast<const int4*>(&kflo[ko]);
        }
        #pragma unroll
        for (int l = 0; l < 2; ++l) {   // SpreT [d][f-slice]: pure int4 copy
            int ch = tid + l * 256;
            int row = ch >> 3, sg = (ch & 7) * 8;
            size_t so = (size_t)(h * NC + c) * FDIM * HD + (size_t)row * FDIM + f0 + sg;
            *reinterpret_cast<int4*>(&T4[row][sg]) = *reinterpret_cast<const int4*>(&SThi[so]);
            *reinterpret_cast<int4*>(&T5[row][sg]) = *reinterpret_cast<const int4*>(&STlo[so]);
        }
        __syncthreads();
        #pragma unroll
        for (int kh = 0; kh < 2; ++kh) {
            const int kb = kh * 32 + lg * 8;
            bf16x8 qh = LD8(T0, wrow + lr, kb), ql = LD8(T1, wrow + lr, kb);
            bf16x8 kh0 = LD8(T2, wcol + lr, kb),      kh1 = LD8(T2, wcol + 16 + lr, kb);
            bf16x8 kl0 = LD8(T3, wcol + lr, kb),      kl1 = LD8(T3, wcol + 16 + lr, kb);
            bf16x8 sh0 = LD8(T4, wcol + lr, kb),      sh1 = LD8(T4, wcol + 16 + lr, kb);
            bf16x8 sl0 = LD8(T5, wcol + lr, kb),      sl1 = LD8(T5, wcol + 16 + lr, kb);
            accA[0] = mm3(qh, ql, kh0, kl0, accA[0]);
            accA[1] = mm3(qh, ql, kh1, kl1, accA[1]);
            accC[0] = mm3(qh, ql, sh0, sl0, accC[0]);
            accC[1] = mm3(qh, ql, sh1, sl1, accC[1]);
            bf16x8 zh8, zl8;
            #pragma unroll
            for (int j = 0; j < 8; ++j) {
                zh8[j] = (short)zhi[f0 + kb + j];
                zl8[j] = (short)zlo[f0 + kb + j];
            }
            accN = mm3(qh, ql, zh8, zl8, accN);
        }
        __syncthreads();
    }

    // phase 2: mask + rowsum + A -> T0/T1 ; Vt planes -> T2/T3 (int4 copies)
    #pragma unroll
    for (int r = 0; r < 4; ++r) {
        int rowl = wrow + lg * 4 + r;
        int rowc = half * 32 + rowl;
        float rs = 0.f;
        #pragma unroll
        for (int j = 0; j < 2; ++j) {
            int col = wcol + j * 16 + lr;
            float vA = (col <= rowc) ? accA[j][r] : 0.f;
            rs += vA;
            unsigned short hv = f2bf(vA);
            T0[rowl][col] = hv;
            T1[rowl][col] = f2bf(vA - bf2f(hv));
        }
        #pragma unroll
        for (int off = 1; off < 16; off <<= 1) rs += __shfl_xor(rs, off, 64);
        if (lr == 0) {
            if ((wid & 1) == 0) nrm_part[0][rowl] = rs + accN[r];
            else                nrm_part[1][rowl] = rs;
        }
    }
    #pragma unroll
    for (int l = 0; l < 4; ++l) {
        int ch = tid + l * 256;
        int plane = ch >> 9, rem = ch & 511;
        int row = rem >> 3, sg = (rem & 7) * 8;
        size_t vo = (size_t)(h * HD + row) * T_LEN + tc0 + sg;
        const unsigned short* src = plane ? Vtlo : Vthi;
        unsigned short (*dst)[80] = plane ? T3 : T2;
        *reinterpret_cast<int4*>(&dst[row][sg]) = *reinterpret_cast<const int4*>(&src[vo]);
    }
    __syncthreads();
    if (tid < 32) nrm[tid] = fmaxf(nrm_part[0][tid] + nrm_part[1][tid], 1e-6f);

    // phase 3: accC += A_masked @ V  (B-op = Vt [d][t], plain reads)
    #pragma unroll
    for (int kh = 0; kh < 2; ++kh) {
        const int kb = kh * 32 + lg * 8;
        bf16x8 ah = LD8(T0, wrow + lr, kb), al = LD8(T1, wrow + lr, kb);
        bf16x8 vh0 = LD8(T2, wcol + lr, kb),      vh1 = LD8(T2, wcol + 16 + lr, kb);
        bf16x8 vl0 = LD8(T3, wcol + lr, kb),      vl1 = LD8(T3, wcol + 16 + lr, kb);
        accC[0] = mm3(ah, al, vh0, vl0, accC[0]);
        accC[1] = mm3(ah, al, vh1, vl1, accC[1]);
    }
    __syncthreads();

    #pragma unroll
    for (int j = 0; j < 2; ++j)
        #pragma unroll
        for (int r = 0; r < 4; ++r) {
            int rowl = wrow + lg * 4 + r;
            int col = wcol + j * 16 + lr;
            float o = accC[j][r] / nrm[rowl];
            unsigned short hv = f2bf(o);
            size_t oi = (size_t)(tq0 + rowl) * EMB + h * HD + col;
            AThi[oi] = hv; ATlo[oi] = f2bf(o - bf2f(hv));
        }
}

// ---------------------------------------------------------------------------
// Workspace ~24.1 MB. Overlays (producer/consumer order audited):
//   AThi/ATlo in Xhi/Xlo  (X read only by k_qkv; AT written by k_attn)
//   Vthi/Vtlo in Whi/Wlo  (W read only by k_qkv; Vt written by k_chunk)
// ---------------------------------------------------------------------------
extern "C" void kernel_launch(void* const* d_in, const int* in_sizes, int n_in,
                              void* d_out, int out_size, void* d_ws, size_t ws_size,
                              hipStream_t stream) {
    const float* x         = (const float*)d_in[0];
    const float* qkv_w     = (const float*)d_in[1];
    const float* qkv_b     = (const float*)d_in[2];
    const float* out_w     = (const float*)d_in[3];
    const float* out_b     = (const float*)d_in[4];
    const float* omega     = (const float*)d_in[5];
    const float* poly_proj = (const float*)d_in[6];
    float* out = (float*)d_out;

    unsigned short* Xhi  = (unsigned short*)d_ws;           // 524288
    unsigned short* Xlo  = Xhi + 524288;
    unsigned short* Whi  = Xlo + 524288;                    // 786432
    unsigned short* Wlo  = Whi + 786432;
    unsigned short* Ohi  = Wlo + 786432;                    // 262144
    unsigned short* Olo  = Ohi + 262144;
    unsigned short* Vhi  = Olo + 262144;                    // 524288
    unsigned short* Vlo  = Vhi + 524288;
    unsigned short* qfhi = Vlo + 524288;                    // 1048576 each
    unsigned short* qflo = qfhi + 1048576;
    unsigned short* kfhi = qflo + 1048576;
    unsigned short* kflo = kfhi + 1048576;
    float* SchT = (float*)(kflo + 1048576);                 // 1048576 f32
    unsigned short* SThi = (unsigned short*)(SchT + 1048576); // 1048576 each
    unsigned short* STlo = SThi + 1048576;
    float* zch  = (float*)(STlo + 1048576);                 // 16384
    float* zpre = zch + 16384;                              // 16384
    unsigned short* AThi = Xhi;                             // overlay
    unsigned short* ATlo = Xlo;                             // overlay
    unsigned short* Vthi = Whi;                             // overlay (1MB in W's 3MB)
    unsigned short* Vtlo = Whi + 524288;                    // overlay

    k_cvt<<<1536, 256, 0, stream>>>(x, qkv_w, out_w, Xhi, Xlo, Whi, Wlo, Ohi, Olo);
    k_qkv_mfma<<<dim3(24, 16), 256, 0, stream>>>(Xhi, Xlo, Whi, Wlo, qkv_b,
                                                 poly_proj, omega, Vhi, Vlo,
                                                 qfhi, qflo, kfhi, kflo);
    k_chunk_kv<<<256, 256, 0, stream>>>(kfhi, kflo, Vhi, Vlo, SchT, zch, Vthi, Vtlo);
    k_prefix<<<128, 256, 0, stream>>>(SchT, zch, SThi, STlo, zpre);
    k_attn_mfma<<<NH * NC * 2, 256, 0, stream>>>(qfhi, qflo, kfhi, kflo, SThi, STlo,
                                                 Vthi, Vtlo, zpre, AThi, ATlo);
    k_out_mfma<<<dim3(8, 16), 256, 0, stream>>>(AThi, ATlo, Ohi, Olo, out_b, out);
}